// Round 9
// baseline (207.438 us; speedup 1.0000x reference)
//
#include <hip/hip_runtime.h>
#include <cstddef>
#include <math.h>

// Problem dims
// B=32, C=1024, T=64, D=64, F_OUT=128, S_DIM=64, N_STG=5, H_MLP=64

typedef __attribute__((ext_vector_type(8))) short bf16x8;
typedef __attribute__((ext_vector_type(4))) float f32x4;

__device__ inline unsigned f2bf(float f) {
  unsigned u = __float_as_uint(f);
  return (u + 0x7FFFu + ((u >> 16) & 1u)) >> 16;   // RTN-even
}

// workspace layout (float offsets)
#define LOGA_OFF 0u          // lam*log(A+eps): 1048576
#define EI_OFF   1048576u    // 32768
#define EJ_OFF   1081344u    // 32768
#define PXG_OFF  1114112u    // partial x_glob: 1024 blocks x 64 = 65536
#define ZK_OFF   1179648u    // bf16 k-major Z: 2097152 floats worth

// ================= K1: mega-fused producer =================
// blocks 0..1023:  32 C-rows each: stream x (mean over T) -> Z GEMV ->
//                  bf16 Zk (k-major) + ei/ej + partial x_glob
// blocks 1024..2047: llogA = lam*log(A+1e-8)
// W is read per-thread straight from global (L1/L2-hot, 32 KB total) --
// no W staging -> LDS 25 KB -> better occupancy than the 41 KB version.
__global__ __launch_bounds__(256) void k_fuse1(
    const float4* __restrict__ X4, const float* __restrict__ A,
    const float* __restrict__ lam, const float* __restrict__ W,
    const float* __restrict__ bproj, const float* __restrict__ att,
    uint4* __restrict__ Zk, float* __restrict__ ei, float* __restrict__ ej,
    float4* __restrict__ pXG4, float* __restrict__ llogA) {
  int tid = threadIdx.x;
  int bk = blockIdx.x;
  if (bk >= 1024) {
    float l = lam[0];
    int base = (bk - 1024) * 1024 + tid;
#pragma unroll
    for (int k = 0; k < 4; ++k)
      llogA[base + k * 256] = l * __logf(A[base + k * 256] + 1e-8f);
    return;
  }
  __shared__ float4 xr4[32 * 16];    // x_red tile [row][dq]  (8 KB)
  __shared__ float Zl[32 * 130];     // fp32 Z tile for ei/ej (16.6 KB)
  int rb = bk * 32;                  // flat row base (b*1024 + c0)

  // stream x: mean over T for this block's 32 rows.
  {
    int row = tid >> 3, g = tid & 7;
    const float4* xbase = X4 + ((size_t)(rb + row)) * 1024 + g;
    float4 a0 = make_float4(0.f, 0.f, 0.f, 0.f), a1 = a0;
#pragma unroll
    for (int k = 0; k < 128; k += 2) {
      float4 v0 = xbase[k * 8];
      float4 v1 = xbase[k * 8 + 8];
      a0.x += v0.x; a0.y += v0.y; a0.z += v0.z; a0.w += v0.w;
      a1.x += v1.x; a1.y += v1.y; a1.z += v1.z; a1.w += v1.w;
    }
    const float inv = 1.0f / 64.0f;
    a0.x *= inv; a0.y *= inv; a0.z *= inv; a0.w *= inv;
    a1.x *= inv; a1.y *= inv; a1.z *= inv; a1.w *= inv;
    xr4[row * 16 + g] = a0;
    xr4[row * 16 + g + 8] = a1;
  }
  __syncthreads();

  // partial x_glob: sum of this block's 32 xr rows
  if (tid < 16) {
    float4 p = make_float4(0.f, 0.f, 0.f, 0.f);
#pragma unroll
    for (int r = 0; r < 32; ++r) {
      float4 v = xr4[r * 16 + tid];
      p.x += v.x; p.y += v.y; p.z += v.z; p.w += v.w;
    }
    pXG4[bk * 16 + tid] = p;
  }

  // GEMV: Z[row][f] = b[f] + xr[row,:] . W[f,:]  (W row direct from global)
  int f = tid & 127, rg = tid >> 7;
  float wreg[64];
  {
    const float4* Wf = (const float4*)(W + f * 64);
#pragma unroll
    for (int q = 0; q < 16; ++q) {
      float4 w = Wf[q];
      wreg[q * 4 + 0] = w.x; wreg[q * 4 + 1] = w.y;
      wreg[q * 4 + 2] = w.z; wreg[q * 4 + 3] = w.w;
    }
  }
  float bias = bproj[f];
  float acc[16];
#pragma unroll
  for (int r = 0; r < 16; ++r) acc[r] = bias;
#pragma unroll
  for (int r = 0; r < 16; ++r) {
    int row = rg * 16 + r;
#pragma unroll
    for (int dq = 0; dq < 16; ++dq) {
      float4 xv = xr4[row * 16 + dq];
      acc[r] = fmaf(wreg[dq * 4 + 0], xv.x, acc[r]);
      acc[r] = fmaf(wreg[dq * 4 + 1], xv.y, acc[r]);
      acc[r] = fmaf(wreg[dq * 4 + 2], xv.z, acc[r]);
      acc[r] = fmaf(wreg[dq * 4 + 3], xv.w, acc[r]);
    }
  }
  // bf16 k-major chunks: Zk[b][c/8][f][c&7]
  int b = rb >> 10;
  int cbase = (rb & 1023) + rg * 16;
#pragma unroll
  for (int k2 = 0; k2 < 2; ++k2) {
    unsigned w0 = f2bf(acc[k2 * 8 + 0]) | (f2bf(acc[k2 * 8 + 1]) << 16);
    unsigned w1 = f2bf(acc[k2 * 8 + 2]) | (f2bf(acc[k2 * 8 + 3]) << 16);
    unsigned w2 = f2bf(acc[k2 * 8 + 4]) | (f2bf(acc[k2 * 8 + 5]) << 16);
    unsigned w3 = f2bf(acc[k2 * 8 + 6]) | (f2bf(acc[k2 * 8 + 7]) << 16);
    size_t chunk = ((size_t)b * 128 + ((cbase >> 3) + k2)) * 128 + f;
    Zk[chunk] = make_uint4(w0, w1, w2, w3);
  }
  // ei/ej tail: stage fp32 Z tile, reduce
#pragma unroll
  for (int r = 0; r < 16; ++r)
    Zl[(rg * 16 + r) * 130 + f] = acc[r];
  __syncthreads();
  int row = tid >> 3, g = tid & 7;   // 32 rows x 8 groups of 16 f
  float si = 0.f, sj = 0.f;
#pragma unroll
  for (int u = 0; u < 16; ++u) {
    float z = Zl[row * 130 + g * 16 + u];
    si = fmaf(z, att[g * 16 + u], si);
    sj = fmaf(z, att[128 + g * 16 + u], sj);
  }
  si += __shfl_xor(si, 1); sj += __shfl_xor(sj, 1);
  si += __shfl_xor(si, 2); sj += __shfl_xor(sj, 2);
  si += __shfl_xor(si, 4); sj += __shfl_xor(sj, 4);
  if (g == 0) { ei[rb + row] = si; ej[rb + row] = sj; }
}

// ================= K2: flash softmax @ Z via MFMA (f-split) =================
// 256 threads = 4 waves per block; block owns (b, rgpair). Wave w handles
// rowgrp = rgpair*2 + (w>>1), f-half = w&1 (4 MFMA frags, 8 Zk loads/tile).
// s/c/ec MLP computed once per block by wave 0, broadcast via LDS.
__global__ __launch_bounds__(256) void k_main(const uint4* __restrict__ Zk,
    const float* __restrict__ llogA, const float* __restrict__ ei,
    const float* __restrict__ ej, const float* __restrict__ pXG,
    const float* __restrict__ Ws1, const float* __restrict__ bs1,
    const float* __restrict__ Ws2, const float* __restrict__ bs2,
    const float* __restrict__ Wc1, const float* __restrict__ bc1,
    const float* __restrict__ Wc2, const float* __restrict__ bc2,
    const float* __restrict__ att,
    float* __restrict__ hout, float* __restrict__ sout) {
  __shared__ float ec_s;
  int bid = blockIdx.x;
  // XCD-bijective decode: xcd = bid&7 owns batches 4*xcd..4*xcd+3
  int b = ((bid & 7) << 2) | ((bid >> 3) & 3);
  int rgpair = bid >> 5;               // 0..31
  int tid = threadIdx.x;
  int wave = tid >> 6, lane = tid & 63;
  int rowgrp = rgpair * 2 + (wave >> 1);
  int fbase = (wave & 1) * 4;          // fragment base (4 frags = 64 f cols)
  int i0 = rowgrp * 16;
  int lg = lane >> 4, ln = lane & 15;

  // ---- pre-phase (wave 0 only): x_glob -> s -> c -> ec ----
  if (wave == 0) {
    float xg = 0.f;
    const float* pb = pXG + (size_t)b * 32 * 64;
#pragma unroll 8
    for (int p = 0; p < 32; ++p) xg += pb[p * 64 + lane];
    xg *= (1.0f / 1024.0f);
    const float* w1 = Ws1 + lane * 64;
    float h = bs1[lane];
#pragma unroll 16
    for (int d = 0; d < 64; ++d) h = fmaf(__shfl(xg, d), w1[d], h);
    h = fmaxf(h, 0.f);
    int ln5 = lane < 5 ? lane : 4;
    const float* w2 = Ws2 + ln5 * 64;
    float l = bs2[ln5];
#pragma unroll 16
    for (int k = 0; k < 64; ++k) l = fmaf(__shfl(h, k), w2[k], l);
    float s0 = __shfl(l, 0), s1 = __shfl(l, 1), s2 = __shfl(l, 2),
          s3 = __shfl(l, 3), s4 = __shfl(l, 4);
    float m = fmaxf(fmaxf(fmaxf(s0, s1), fmaxf(s2, s3)), s4);
    float e0 = __expf(s0 - m), e1 = __expf(s1 - m), e2 = __expf(s2 - m),
          e3 = __expf(s3 - m), e4 = __expf(s4 - m);
    float inv = 1.0f / (e0 + e1 + e2 + e3 + e4);
    s0 = e0 * inv; s1 = e1 * inv; s2 = e2 * inv; s3 = e3 * inv; s4 = e4 * inv;
    if (rgpair == 0 && lane == 0) {
      sout[b * 5 + 0] = s0; sout[b * 5 + 1] = s1; sout[b * 5 + 2] = s2;
      sout[b * 5 + 3] = s3; sout[b * 5 + 4] = s4;
    }
    const float* wc1 = Wc1 + lane * 5;
    float cv = bc1[lane];
    cv = fmaf(s0, wc1[0], cv); cv = fmaf(s1, wc1[1], cv);
    cv = fmaf(s2, wc1[2], cv); cv = fmaf(s3, wc1[3], cv);
    cv = fmaf(s4, wc1[4], cv);
    cv = fmaxf(cv, 0.f);
    const float* wc2 = Wc2 + lane * 64;
    float c2 = bc2[lane];
#pragma unroll 16
    for (int k = 0; k < 64; ++k) c2 = fmaf(__shfl(cv, k), wc2[k], c2);
    float v = c2 * att[256 + lane];
#pragma unroll
    for (int o = 32; o; o >>= 1) v += __shfl_xor(v, o);
    if (lane == 0) ec_s = v;
  }
  __syncthreads();
  float ecb = ec_s;

  // ---- flash loop ----
  int i_gl = i0 + ln;
  float eir = ei[b * 1024 + i_gl];
  const float4* lrow4 = (const float4*)(llogA + (size_t)i_gl * 1024);
  const float4* ejr4  = (const float4*)(ej + b * 1024);
  const uint4*  ZkB   = Zk + (size_t)b * 128 * 128;

  float m_run = -1e30f, s_run = 0.0f;
  f32x4 acc[4];
#pragma unroll
  for (int q = 0; q < 4; ++q) { f32x4 z = {0.f, 0.f, 0.f, 0.f}; acc[q] = z; }

  for (int jt = 0; jt < 16; ++jt) {
    int j0 = jt * 64;
    uint4 bz[2][4];
#pragma unroll
    for (int ks = 0; ks < 2; ++ks)
#pragma unroll
      for (int fb = 0; fb < 4; ++fb)
        bz[ks][fb] = ZkB[(size_t)((j0 >> 3) + ks * 4 + lg) * 128
                         + (fbase + fb) * 16 + ln];
    float tv[16];
    float tm = -1e30f;
#pragma unroll
    for (int ks = 0; ks < 2; ++ks) {
      int jb = (j0 + ks * 32 + lg * 8) >> 2;
      float4 e0 = ejr4[jb], e1 = ejr4[jb + 1];
      float4 l0 = lrow4[jb], l1 = lrow4[jb + 1];
      float eq[8] = {e0.x, e0.y, e0.z, e0.w, e1.x, e1.y, e1.z, e1.w};
      float lq[8] = {l0.x, l0.y, l0.z, l0.w, l1.x, l1.y, l1.z, l1.w};
#pragma unroll
      for (int u = 0; u < 8; ++u) {
        float t = eir + eq[u] + ecb;
        t = t > 0.0f ? t : 0.2f * t;          // leaky_relu(0.2)
        t += lq[u];                            // + lam*log(A+eps)
        tv[ks * 8 + u] = t;
        tm = fmaxf(tm, t);
      }
    }
    tm = fmaxf(tm, __shfl_xor(tm, 16));
    tm = fmaxf(tm, __shfl_xor(tm, 32));
    // defer-rescale: skip when no row's max grew (scale == 1 exactly)
    float newm = fmaxf(m_run, tm);
    if (!__all(tm <= m_run)) {
      float scale = __expf(m_run - newm);
      s_run *= scale;
#pragma unroll
      for (int q = 0; q < 4; ++q) acc[q] *= scale;
      m_run = newm;
    }
    float ts = 0.0f;
    unsigned pw[8];
#pragma unroll
    for (int q = 0; q < 8; ++q) {
      float p0 = __expf(tv[2 * q] - m_run);
      float p1 = __expf(tv[2 * q + 1] - m_run);
      ts += p0 + p1;
      pw[q] = f2bf(p0) | (f2bf(p1) << 16);
    }
    ts += __shfl_xor(ts, 16);
    ts += __shfl_xor(ts, 32);
    s_run += ts;
    union { unsigned u[4]; bf16x8 v; } c0, c1;
#pragma unroll
    for (int q = 0; q < 4; ++q) { c0.u[q] = pw[q]; c1.u[q] = pw[4 + q]; }
#pragma unroll
    for (int fb = 0; fb < 4; ++fb)
      acc[fb] = __builtin_amdgcn_mfma_f32_16x16x32_bf16(c0.v, *(bf16x8*)&bz[0][fb], acc[fb], 0, 0, 0);
#pragma unroll
    for (int fb = 0; fb < 4; ++fb)
      acc[fb] = __builtin_amdgcn_mfma_f32_16x16x32_bf16(c1.v, *(bf16x8*)&bz[1][fb], acc[fb], 0, 0, 0);
  }

  // epilogue: normalize by D-row 1/s, write out
  float invs = 1.0f / s_run;
  float inv_m[4];
#pragma unroll
  for (int r = 0; r < 4; ++r) inv_m[r] = __shfl(invs, lg * 4 + r);
  float* hb = hout + ((size_t)b * 1024 + i0 + lg * 4) * 128 + fbase * 16 + ln;
#pragma unroll
  for (int fb = 0; fb < 4; ++fb) {
#pragma unroll
    for (int r = 0; r < 4; ++r)
      hb[(size_t)r * 128 + fb * 16] = acc[fb][r] * inv_m[r];
  }
}

extern "C" void kernel_launch(void* const* d_in, const int* in_sizes, int n_in,
                              void* d_out, int out_size, void* d_ws, size_t ws_size,
                              hipStream_t stream) {
  const float* x     = (const float*)d_in[0];
  const float* Ainit = (const float*)d_in[1];
  const float* Wproj = (const float*)d_in[2];
  const float* bproj = (const float*)d_in[3];
  const float* Ws1   = (const float*)d_in[4];
  const float* bs1   = (const float*)d_in[5];
  const float* Ws2   = (const float*)d_in[6];
  const float* bs2   = (const float*)d_in[7];
  const float* Wc1   = (const float*)d_in[8];
  const float* bc1   = (const float*)d_in[9];
  const float* Wc2   = (const float*)d_in[10];
  const float* bc2   = (const float*)d_in[11];
  const float* att   = (const float*)d_in[12];
  const float* lam   = (const float*)d_in[13];

  float* ws    = (float*)d_ws;
  float* llogA = ws + LOGA_OFF;
  float* ei    = ws + EI_OFF;
  float* ej    = ws + EJ_OFF;
  float* pXG   = ws + PXG_OFF;
  uint4* Zk    = (uint4*)(ws + ZK_OFF);

  float* hout = (float*)d_out;                  // (32,1024,128)
  float* sout = hout + (size_t)32 * 1024 * 128; // (32,5)

  hipLaunchKernelGGL(k_fuse1, dim3(2048), dim3(256), 0, stream,
                     (const float4*)x, Ainit, lam, Wproj, bproj, att,
                     Zk, ei, ej, (float4*)pXG, llogA);
  hipLaunchKernelGGL(k_main,  dim3(1024), dim3(256), 0, stream,
                     Zk, llogA, ei, ej, pXG,
                     Ws1, bs1, Ws2, bs2, Wc1, bc1, Wc2, bc2, att,
                     hout, sout);
}

// Round 10
// 183.740 us; speedup vs baseline: 1.1290x; 1.1290x over previous
//
#include <hip/hip_runtime.h>
#include <cstddef>
#include <math.h>

// Problem dims
// B=32, C=1024, T=64, D=64, F_OUT=128, S_DIM=64, N_STG=5, H_MLP=64

typedef __attribute__((ext_vector_type(8))) short bf16x8;
typedef __attribute__((ext_vector_type(4))) float f32x4;

__device__ inline unsigned f2bf(float f) {
  unsigned u = __float_as_uint(f);
  return (u + 0x7FFFu + ((u >> 16) & 1u)) >> 16;   // RTN-even
}

// workspace layout (float offsets)
#define LOGA_OFF 0u          // lam*log(A+eps): 1048576
#define EI_OFF   1048576u    // 32768
#define EJ_OFF   1081344u    // 32768
#define PXG_OFF  1114112u    // partial x_glob: 1024 blocks x 64 = 65536
#define ZK_OFF   1179648u    // bf16 k-major Z: 2097152 floats worth

// ================= K1: mega-fused producer (R8-exact) =================
// blocks 0..1023:  32 C-rows each: stream x (mean over T) -> Z GEMV ->
//                  bf16 Zk (k-major) + ei/ej + partial x_glob
// blocks 1024..2047: llogA = lam*log(A+1e-8)
__global__ __launch_bounds__(256) void k_fuse1(
    const float4* __restrict__ X4, const float* __restrict__ A,
    const float* __restrict__ lam, const float* __restrict__ W,
    const float* __restrict__ bproj, const float* __restrict__ att,
    uint4* __restrict__ Zk, float* __restrict__ ei, float* __restrict__ ej,
    float4* __restrict__ pXG4, float* __restrict__ llogA) {
  int tid = threadIdx.x;
  int bk = blockIdx.x;
  if (bk >= 1024) {
    float l = lam[0];
    int base = (bk - 1024) * 1024 + tid;
#pragma unroll
    for (int k = 0; k < 4; ++k)
      llogA[base + k * 256] = l * __logf(A[base + k * 256] + 1e-8f);
    return;
  }
  __shared__ float Wl[64 * 129];     // W transposed [d][f]; reused as Zl[32][130]
  __shared__ float4 xr4[32 * 16];    // x_red tile [row][dq]
  int rb = bk * 32;                  // flat row base (b*1024 + c0)

  // stage W transposed (L2-hot after first blocks)
#pragma unroll
  for (int k = 0; k < 32; ++k) {
    int g = k * 256 + tid;           // g = f*64 + d
    Wl[(g & 63) * 129 + (g >> 6)] = W[g];
  }

  // stream x: mean over T for this block's 32 rows.
  {
    int row = tid >> 3, g = tid & 7;
    const float4* xbase = X4 + ((size_t)(rb + row)) * 1024 + g;
    float4 a0 = make_float4(0.f, 0.f, 0.f, 0.f), a1 = a0;
#pragma unroll
    for (int k = 0; k < 128; k += 2) {
      float4 v0 = xbase[k * 8];
      float4 v1 = xbase[k * 8 + 8];
      a0.x += v0.x; a0.y += v0.y; a0.z += v0.z; a0.w += v0.w;
      a1.x += v1.x; a1.y += v1.y; a1.z += v1.z; a1.w += v1.w;
    }
    const float inv = 1.0f / 64.0f;
    a0.x *= inv; a0.y *= inv; a0.z *= inv; a0.w *= inv;
    a1.x *= inv; a1.y *= inv; a1.z *= inv; a1.w *= inv;
    xr4[row * 16 + g] = a0;
    xr4[row * 16 + g + 8] = a1;
  }
  __syncthreads();

  // partial x_glob: sum of this block's 32 xr rows
  if (tid < 16) {
    float4 p = make_float4(0.f, 0.f, 0.f, 0.f);
#pragma unroll
    for (int r = 0; r < 32; ++r) {
      float4 v = xr4[r * 16 + tid];
      p.x += v.x; p.y += v.y; p.z += v.z; p.w += v.w;
    }
    pXG4[bk * 16 + tid] = p;
  }

  // GEMV: Z[row][f] = b[f] + xr[row,:] . W[f,:]
  int f = tid & 127, rg = tid >> 7;
  float wreg[64];
#pragma unroll
  for (int d = 0; d < 64; ++d) wreg[d] = Wl[d * 129 + f];
  float bias = bproj[f];
  float acc[16];
#pragma unroll
  for (int r = 0; r < 16; ++r) acc[r] = bias;
#pragma unroll
  for (int r = 0; r < 16; ++r) {
    int row = rg * 16 + r;
#pragma unroll
    for (int dq = 0; dq < 16; ++dq) {
      float4 xv = xr4[row * 16 + dq];
      acc[r] = fmaf(wreg[dq * 4 + 0], xv.x, acc[r]);
      acc[r] = fmaf(wreg[dq * 4 + 1], xv.y, acc[r]);
      acc[r] = fmaf(wreg[dq * 4 + 2], xv.z, acc[r]);
      acc[r] = fmaf(wreg[dq * 4 + 3], xv.w, acc[r]);
    }
  }
  // bf16 k-major chunks: Zk[b][c/8][f][c&7]
  int b = rb >> 10;
  int cbase = (rb & 1023) + rg * 16;
#pragma unroll
  for (int k2 = 0; k2 < 2; ++k2) {
    unsigned w0 = f2bf(acc[k2 * 8 + 0]) | (f2bf(acc[k2 * 8 + 1]) << 16);
    unsigned w1 = f2bf(acc[k2 * 8 + 2]) | (f2bf(acc[k2 * 8 + 3]) << 16);
    unsigned w2 = f2bf(acc[k2 * 8 + 4]) | (f2bf(acc[k2 * 8 + 5]) << 16);
    unsigned w3 = f2bf(acc[k2 * 8 + 6]) | (f2bf(acc[k2 * 8 + 7]) << 16);
    size_t chunk = ((size_t)b * 128 + ((cbase >> 3) + k2)) * 128 + f;
    Zk[chunk] = make_uint4(w0, w1, w2, w3);
  }
  // ei/ej tail: stage fp32 Z tile into LDS (reuse Wl), reduce
  __syncthreads();                   // all Wl/xr4 reads done
  float* Zl = Wl;                    // [32][130]
#pragma unroll
  for (int r = 0; r < 16; ++r)
    Zl[(rg * 16 + r) * 130 + f] = acc[r];
  __syncthreads();
  int row = tid >> 3, g = tid & 7;   // 32 rows x 8 groups of 16 f
  float si = 0.f, sj = 0.f;
#pragma unroll
  for (int u = 0; u < 16; ++u) {
    float z = Zl[row * 130 + g * 16 + u];
    si = fmaf(z, att[g * 16 + u], si);
    sj = fmaf(z, att[128 + g * 16 + u], sj);
  }
  si += __shfl_xor(si, 1); sj += __shfl_xor(sj, 1);
  si += __shfl_xor(si, 2); sj += __shfl_xor(sj, 2);
  si += __shfl_xor(si, 4); sj += __shfl_xor(sj, 4);
  if (g == 0) { ei[rb + row] = si; ej[rb + row] = sj; }
}

// ================= K2: flash softmax @ Z via MFMA (R8 + prefetch) =================
// One independent wave per (b, 16-row group). 1-wave blocks, no inter-wave sync.
// NEW vs R8: register double-buffer prefetches next tile's Zk fragments (16 b128)
// and llogA chunks (4 float4) one tile ahead; ej[b] staged once in LDS.
// Math is bit-identical to R8 (always-rescale; __expf(0)==1 exact).
__global__ __launch_bounds__(64) void k_main(const uint4* __restrict__ Zk,
    const float* __restrict__ llogA, const float* __restrict__ ei,
    const float* __restrict__ ej, const float* __restrict__ pXG,
    const float* __restrict__ Ws1, const float* __restrict__ bs1,
    const float* __restrict__ Ws2, const float* __restrict__ bs2,
    const float* __restrict__ Wc1, const float* __restrict__ bc1,
    const float* __restrict__ Wc2, const float* __restrict__ bc2,
    const float* __restrict__ att,
    float* __restrict__ hout, float* __restrict__ sout) {
  __shared__ float4 ejs4[256];         // ej[b][0..1023]
  int bid = blockIdx.x;
  // XCD-bijective decode: all 64 row-groups of a batch land on one XCD
  int b = ((bid & 7) << 2) | ((bid >> 3) & 3);
  int rowgrp = bid >> 5;               // 0..63
  int i0 = rowgrp * 16;
  int lane = threadIdx.x;
  int lg = lane >> 4, ln = lane & 15;

  // stage ej[b] (4 KB) into LDS
  const float4* ej4 = (const float4*)(ej + b * 1024);
#pragma unroll
  for (int k = 0; k < 4; ++k) ejs4[k * 64 + lane] = ej4[k * 64 + lane];
  __syncthreads();                     // 1-wave block: cheap, orders ds_write->ds_read

  // ---- pre-phase: x_glob -> s -> c -> ec (shfl-based, wave-local) ----
  float ecb;
  {
    float xg = 0.f;
    const float* pb = pXG + (size_t)b * 32 * 64;
#pragma unroll 8
    for (int p = 0; p < 32; ++p) xg += pb[p * 64 + lane];
    xg *= (1.0f / 1024.0f);
    const float* w1 = Ws1 + lane * 64;
    float h = bs1[lane];
#pragma unroll 16
    for (int d = 0; d < 64; ++d) h = fmaf(__shfl(xg, d), w1[d], h);
    h = fmaxf(h, 0.f);
    int ln5 = lane < 5 ? lane : 4;
    const float* w2 = Ws2 + ln5 * 64;
    float l = bs2[ln5];
#pragma unroll 16
    for (int k = 0; k < 64; ++k) l = fmaf(__shfl(h, k), w2[k], l);
    float s0 = __shfl(l, 0), s1 = __shfl(l, 1), s2 = __shfl(l, 2),
          s3 = __shfl(l, 3), s4 = __shfl(l, 4);
    float m = fmaxf(fmaxf(fmaxf(s0, s1), fmaxf(s2, s3)), s4);
    float e0 = __expf(s0 - m), e1 = __expf(s1 - m), e2 = __expf(s2 - m),
          e3 = __expf(s3 - m), e4 = __expf(s4 - m);
    float inv = 1.0f / (e0 + e1 + e2 + e3 + e4);
    s0 = e0 * inv; s1 = e1 * inv; s2 = e2 * inv; s3 = e3 * inv; s4 = e4 * inv;
    if (rowgrp == 0 && lane == 0) {
      sout[b * 5 + 0] = s0; sout[b * 5 + 1] = s1; sout[b * 5 + 2] = s2;
      sout[b * 5 + 3] = s3; sout[b * 5 + 4] = s4;
    }
    const float* wc1 = Wc1 + lane * 5;
    float cv = bc1[lane];
    cv = fmaf(s0, wc1[0], cv); cv = fmaf(s1, wc1[1], cv);
    cv = fmaf(s2, wc1[2], cv); cv = fmaf(s3, wc1[3], cv);
    cv = fmaf(s4, wc1[4], cv);
    cv = fmaxf(cv, 0.f);
    const float* wc2 = Wc2 + lane * 64;
    float c2 = bc2[lane];
#pragma unroll 16
    for (int k = 0; k < 64; ++k) c2 = fmaf(__shfl(cv, k), wc2[k], c2);
    float v = c2 * att[256 + lane];
#pragma unroll
    for (int o = 32; o; o >>= 1) v += __shfl_xor(v, o);
    ecb = v;
  }

  // ---- flash loop with 1-tile-ahead register prefetch ----
  int i_gl = i0 + ln;
  float eir = ei[b * 1024 + i_gl];
  const float4* lrow4 = (const float4*)(llogA + (size_t)i_gl * 1024);
  const uint4*  ZkB   = Zk + (size_t)b * 128 * 128;

  float m_run = -1e30f, s_run = 0.0f;
  f32x4 acc[8];
#pragma unroll
  for (int q = 0; q < 8; ++q) { f32x4 z = {0.f, 0.f, 0.f, 0.f}; acc[q] = z; }

#define LOAD_BZ(buf, jt_) do { int j0_ = (jt_) * 64;                          \
  _Pragma("unroll") for (int ks = 0; ks < 2; ++ks)                            \
    _Pragma("unroll") for (int fb = 0; fb < 8; ++fb)                          \
      buf[ks][fb] = ZkB[(size_t)((j0_ >> 3) + ks * 4 + lg) * 128              \
                        + fb * 16 + ln];                                      \
} while (0)

#define LOAD_LA(buf, jt_) do { int j0_ = (jt_) * 64;                          \
  _Pragma("unroll") for (int ks = 0; ks < 2; ++ks) {                          \
    int jb = (j0_ + ks * 32 + lg * 8) >> 2;                                   \
    buf[ks][0] = lrow4[jb]; buf[ks][1] = lrow4[jb + 1]; }                     \
} while (0)

#define PROCESS(jt_, bz, la) do { int j0_ = (jt_) * 64;                       \
  float tv[16]; float tm = -1e30f;                                            \
  _Pragma("unroll") for (int ks = 0; ks < 2; ++ks) {                          \
    int jb = (j0_ + ks * 32 + lg * 8) >> 2;                                   \
    float4 e0 = ejs4[jb], e1 = ejs4[jb + 1];                                  \
    float4 l0 = la[ks][0], l1 = la[ks][1];                                    \
    float eq[8] = {e0.x, e0.y, e0.z, e0.w, e1.x, e1.y, e1.z, e1.w};           \
    float lq[8] = {l0.x, l0.y, l0.z, l0.w, l1.x, l1.y, l1.z, l1.w};           \
    _Pragma("unroll") for (int u = 0; u < 8; ++u) {                           \
      float t = eir + eq[u] + ecb;                                            \
      t = t > 0.0f ? t : 0.2f * t;                                            \
      t += lq[u];                                                             \
      tv[ks * 8 + u] = t; tm = fmaxf(tm, t); } }                              \
  tm = fmaxf(tm, __shfl_xor(tm, 16));                                         \
  tm = fmaxf(tm, __shfl_xor(tm, 32));                                         \
  float newm = fmaxf(m_run, tm);                                              \
  float scale = __expf(m_run - newm);                                         \
  float ts = 0.0f; unsigned pw[8];                                            \
  _Pragma("unroll") for (int q = 0; q < 8; ++q) {                             \
    float p0 = __expf(tv[2 * q] - newm);                                      \
    float p1 = __expf(tv[2 * q + 1] - newm);                                  \
    ts += p0 + p1; pw[q] = f2bf(p0) | (f2bf(p1) << 16); }                     \
  ts += __shfl_xor(ts, 16); ts += __shfl_xor(ts, 32);                         \
  s_run = s_run * scale + ts; m_run = newm;                                   \
  _Pragma("unroll") for (int q = 0; q < 8; ++q) acc[q] *= scale;              \
  union { unsigned u[4]; bf16x8 v; } c0, c1;                                  \
  _Pragma("unroll") for (int q = 0; q < 4; ++q) {                             \
    c0.u[q] = pw[q]; c1.u[q] = pw[4 + q]; }                                   \
  _Pragma("unroll") for (int fb = 0; fb < 8; ++fb)                            \
    acc[fb] = __builtin_amdgcn_mfma_f32_16x16x32_bf16(                        \
        c0.v, *(bf16x8*)&bz[0][fb], acc[fb], 0, 0, 0);                        \
  _Pragma("unroll") for (int fb = 0; fb < 8; ++fb)                            \
    acc[fb] = __builtin_amdgcn_mfma_f32_16x16x32_bf16(                        \
        c1.v, *(bf16x8*)&bz[1][fb], acc[fb], 0, 0, 0);                        \
} while (0)

  uint4 bzA[2][8], bzB[2][8];
  float4 laA[2][2], laB[2][2];
  LOAD_BZ(bzA, 0);
  LOAD_LA(laA, 0);
  for (int jt = 0; jt < 16; jt += 2) {
    LOAD_BZ(bzB, jt + 1);
    LOAD_LA(laB, jt + 1);
    PROCESS(jt, bzA, laA);
    if (jt + 2 < 16) {
      LOAD_BZ(bzA, jt + 2);
      LOAD_LA(laA, jt + 2);
    }
    PROCESS(jt + 1, bzB, laB);
  }
#undef LOAD_BZ
#undef LOAD_LA
#undef PROCESS

  // epilogue: normalize by D-row 1/s, write out
  float invs = 1.0f / s_run;
  float inv_m[4];
#pragma unroll
  for (int r = 0; r < 4; ++r) inv_m[r] = __shfl(invs, lg * 4 + r);
  float* hb = hout + ((size_t)b * 1024 + i0 + lg * 4) * 128 + ln;
#pragma unroll
  for (int fb = 0; fb < 8; ++fb) {
#pragma unroll
    for (int r = 0; r < 4; ++r)
      hb[(size_t)r * 128 + fb * 16] = acc[fb][r] * inv_m[r];
  }
}

extern "C" void kernel_launch(void* const* d_in, const int* in_sizes, int n_in,
                              void* d_out, int out_size, void* d_ws, size_t ws_size,
                              hipStream_t stream) {
  const float* x     = (const float*)d_in[0];
  const float* Ainit = (const float*)d_in[1];
  const float* Wproj = (const float*)d_in[2];
  const float* bproj = (const float*)d_in[3];
  const float* Ws1   = (const float*)d_in[4];
  const float* bs1   = (const float*)d_in[5];
  const float* Ws2   = (const float*)d_in[6];
  const float* bs2   = (const float*)d_in[7];
  const float* Wc1   = (const float*)d_in[8];
  const float* bc1   = (const float*)d_in[9];
  const float* Wc2   = (const float*)d_in[10];
  const float* bc2   = (const float*)d_in[11];
  const float* att   = (const float*)d_in[12];
  const float* lam   = (const float*)d_in[13];

  float* ws    = (float*)d_ws;
  float* llogA = ws + LOGA_OFF;
  float* ei    = ws + EI_OFF;
  float* ej    = ws + EJ_OFF;
  float* pXG   = ws + PXG_OFF;
  uint4* Zk    = (uint4*)(ws + ZK_OFF);

  float* hout = (float*)d_out;                  // (32,1024,128)
  float* sout = hout + (size_t)32 * 1024 * 128; // (32,5)

  hipLaunchKernelGGL(k_fuse1, dim3(2048), dim3(256), 0, stream,
                     (const float4*)x, Ainit, lam, Wproj, bproj, att,
                     Zk, ei, ej, (float4*)pXG, llogA);
  hipLaunchKernelGGL(k_main,  dim3(2048), dim3(64),  0, stream,
                     Zk, llogA, ei, ej, pXG,
                     Ws1, bs1, Ws2, bs2, Wc1, bc1, Wc2, bc2, att,
                     hout, sout);
}